// Round 3
// baseline (506.616 us; speedup 1.0000x reference)
//
#include <hip/hip_runtime.h>

// SparseEmbedding forward: out[(b,h), :] = weight[idx[(b,h)], :]
// NE = 1,000,000 rows, C = 64 floats/row (256 B), NROWS = 4096*50 = 204,800.
//
// R3: same as R2 but using a native clang vector type (ext_vector_type) so
// __builtin_nontemporal_store accepts it. 16 lanes/row (16 B per lane),
// 4 rows per thread (strided unroll) for MLP, nontemporal write-once stores.

typedef float vfloat4 __attribute__((ext_vector_type(4)));

__global__ __launch_bounds__(256) void SparseEmbedding_69011534512743_kernel(
    const int* __restrict__ indices,       // NROWS entries (int32)
    const vfloat4* __restrict__ weight,    // NE rows * 16 vfloat4
    vfloat4* __restrict__ out,             // NROWS rows * 16 vfloat4
    int nrows, int row_stride)             // row_stride = ceil(nrows/4)
{
    const int tid   = blockIdx.x * blockDim.x + threadIdx.x;
    const int chunk = tid & 15;            // vfloat4 slot within the 256 B row
    const int row0  = tid >> 4;

    int  rowv[4];
    int  r[4];
    bool ok[4];
    #pragma unroll
    for (int k = 0; k < 4; ++k) {
        rowv[k] = row0 + k * row_stride;
        ok[k]   = rowv[k] < nrows;
        r[k]    = ok[k] ? indices[rowv[k]] : 0;   // 4 independent index loads
    }

    vfloat4 v[4];
    #pragma unroll
    for (int k = 0; k < 4; ++k) {
        if (ok[k]) v[k] = weight[(size_t)r[k] * 16 + chunk];  // 4 independent gathers
    }

    #pragma unroll
    for (int k = 0; k < 4; ++k) {
        if (ok[k])
            __builtin_nontemporal_store(v[k], &out[(size_t)rowv[k] * 16 + chunk]);
    }
}

extern "C" void kernel_launch(void* const* d_in, const int* in_sizes, int n_in,
                              void* d_out, int out_size, void* d_ws, size_t ws_size,
                              hipStream_t stream) {
    const int*     indices = (const int*)d_in[0];      // (B*H,) int
    const vfloat4* weight  = (const vfloat4*)d_in[1];  // (NE, 64) f32 -> 16/row
    vfloat4*       out     = (vfloat4*)d_out;          // (B*H, 64) f32

    const int nrows      = in_sizes[0];                // 204,800
    const int row_stride = (nrows + 3) / 4;            // 51,200
    const int total_threads = row_stride * 16;
    const int block = 256;
    const int grid  = (total_threads + block - 1) / block;

    SparseEmbedding_69011534512743_kernel<<<grid, block, 0, stream>>>(
        indices, weight, out, nrows, row_stride);
}